// Round 12
// baseline (379.911 us; speedup 1.0000x reference)
//
#include <hip/hip_runtime.h>

#define BATCH 4096
#define TT 512
#define HH 64
#define XS 516     // x_s row stride in floats
#define HS 72      // h buffer row stride in bf16

typedef __attribute__((ext_vector_type(8))) short short8;
typedef __attribute__((ext_vector_type(4))) float floatx4;

__device__ __forceinline__ unsigned short f2bf(float f) {   // RNE f32->bf16
    unsigned u = __float_as_uint(f);
    u = u + 0x7FFFu + ((u >> 16) & 1u);
    return (unsigned short)(u >> 16);
}

// CHAIN-FREE INTERVALS. R5/R9/R11 all walled at ~1164 cyc/step because the
// serial chain (barrier->ds_read->MFMA->act->write->barrier) ran inside every
// interval. Here the block carries TWO independent 8-row recurrences P,Q
// (16 batch rows, tile rows 4*(j>>1)+(j&1), lanes own slots r=0,1; no MFMA
// duplication). Intervals alternate:
//   even: act_P(k)[acc from last interval] ; write h_P(k) ; MFMA_Q(k)[frags
//         read last interval] ; barrier ; read h_P(k) frags
//   odd:  act_Q(k) ; write h_Q(k) ; MFMA_P(k+1) ; barrier ; read h_Q(k) frags
// Every producer->consumer edge spans a barrier: ds_read latency, MFMA pipe
// drain and the act chain are all hidden under the other group's work.
// h single-buffered per group: reads of h_G(k) and the write of h_G(k+1) are
// separated by the opposite group's barrier. Grid 256 = 1 block/CU, 4 waves.
__global__ __launch_bounds__(256, 1) void lstm_kernel(
    const float* __restrict__ x, const float* __restrict__ W_ih,
    const float* __restrict__ W_hh, const float* __restrict__ b_ih,
    const float* __restrict__ b_hh, const float* __restrict__ W_out,
    const float* __restrict__ b_out, float* __restrict__ out)
{
    __shared__ __align__(16) float x_s[16 * XS];            // 33 KB
    __shared__ __align__(16) unsigned short hP[16 * HS];    // group P h (rows m&2 stay 0)
    __shared__ __align__(16) unsigned short hQ[16 * HS];    // group Q h
    __shared__ __align__(16) float hf[16 * 65];

    const int tid = threadIdx.x;
    const int w = tid >> 6;       // wave 0..3 -> gate col-tiles {w,w+4,w+8,w+12}
    const int l = tid & 63;
    const int q = l >> 4;
    const int c = l & 15;
    const int n = 16 * w + c;     // hidden index this lane activates
    const int bbase = blockIdx.x * 16;

    // stage x[bbase..bbase+15][0..511] into LDS, coalesced float4
    for (int i = 0; i < 8; ++i) {
        int flat = i * 256 + tid;              // 2048 float4s
        int row = flat >> 7, c4 = flat & 127;
        const float4* xg = reinterpret_cast<const float4*>(x + (size_t)(bbase + row) * TT);
        float4 v = xg[c4];
        *reinterpret_cast<float4*>(&x_s[row * XS + c4 * 4]) = v;
    }
    for (int i = tid; i < 16 * HS; i += 256) { hP[i] = 0; hQ[i] = 0; }

    const float L1 = 1.44269504089f;      // log2(e)
    const float L2 = 2.88539008178f;      // 2*log2(e)

    // persistent B-fragments, PRE-SCALED (i,f,o: -log2e ; g: +2log2e), bf16
    short8 bfr[4][2];
    float wih[4], bb[4];
    for (int t = 0; t < 4; ++t) {
        float sc = (t == 2) ? L2 : -L1;
        int g = 64 * t + n;
        wih[t] = W_ih[g] * sc;
        bb[t] = (b_ih[g] + b_hh[g]) * sc;
        for (int ks = 0; ks < 2; ++ks) {
            const float* wp = W_hh + g * 64 + ks * 32 + q * 8;
            short8 v;
            #pragma unroll
            for (int j = 0; j < 8; ++j) v[j] = (short)f2bf(wp[j] * sc);
            bfr[t][ks] = v;
        }
    }

    float csP[2] = {0.f, 0.f}, csQ[2] = {0.f, 0.f};
    float hvP[2], hvQ[2];
    floatx4 acP[4], acQ[4];       // slots r=2,3 face zero A-rows: stay 0 forever
    #pragma unroll
    for (int t = 0; t < 4; ++t) { acP[t] = floatx4{0.f,0.f,0.f,0.f}; acQ[t] = floatx4{0.f,0.f,0.f,0.f}; }

    const int aoff = c * HS + q * 8;      // A-frag LDS offset (shorts)
    const int woff = (4 * q) * HS + n;    // h write base; +HS for rr=1
    const float* xP0 = &x_s[(2 * q) * XS];        // P rows 2q, 2q+1
    const float* xP1 = &x_s[(2 * q + 1) * XS];
    const float* xQ0 = &x_s[(8 + 2 * q) * XS];    // Q rows 8+2q, 8+2q+1
    const float* xQ1 = &x_s[(8 + 2 * q + 1) * XS];

    __syncthreads();   // staging + zeroed h visible

    #define ACT(ACC, CST, HV) do {                                              \
        _Pragma("unroll")                                                       \
        for (int rr = 0; rr < 2; ++rr) {                                        \
            float ei = __builtin_amdgcn_exp2f(ACC[0][rr]);                      \
            float ef = __builtin_amdgcn_exp2f(ACC[1][rr]);                      \
            float eg = __builtin_amdgcn_exp2f(ACC[2][rr]);                      \
            float eo = __builtin_amdgcn_exp2f(ACC[3][rr]);                      \
            float pf1 = 1.f + ef, pig = (1.f + ei) * (1.f + eg);                \
            float num = fmaf(CST[rr], pig, (eg - 1.f) * pf1);                   \
            CST[rr] = num * __builtin_amdgcn_rcpf(pf1 * pig);                   \
            float ec = __builtin_amdgcn_exp2f(L2 * CST[rr]);                    \
            HV[rr] = (ec - 1.f) * __builtin_amdgcn_rcpf((1.f + eo) * (1.f + ec)); \
        } } while (0)

    // Prologue: h(-1)=0 -> acc_P(0) = x_proj only; Q frags read from zeroed hQ
    short8 aP0, aP1, aQ0, aQ1;
    aQ0 = *reinterpret_cast<const short8*>(hQ + aoff);
    aQ1 = *reinterpret_cast<const short8*>(hQ + aoff + 32);
    {
        float x0 = xP0[0], x1 = xP1[0];
        #pragma unroll
        for (int t = 0; t < 4; ++t) {
            acP[t][0] = fmaf(x0, wih[t], bb[t]);
            acP[t][1] = fmaf(x1, wih[t], bb[t]);
        }
    }

    for (int k = 0; k < TT; ++k) {
        // ---- even interval: act P(k), MFMA Q(k) ----
        float xq0 = xQ0[k], xq1 = xQ1[k];          // for MFMA_Q init (issued early)
        ACT(acP, csP, hvP);
        hP[woff] = f2bf(hvP[0]); hP[woff + HS] = f2bf(hvP[1]);
        #pragma unroll
        for (int t = 0; t < 4; ++t) {
            acQ[t][0] = fmaf(xq0, wih[t], bb[t]);
            acQ[t][1] = fmaf(xq1, wih[t], bb[t]);
        }
        #pragma unroll
        for (int t = 0; t < 4; ++t) {
            acQ[t] = __builtin_amdgcn_mfma_f32_16x16x32_bf16(aQ0, bfr[t][0], acQ[t], 0, 0, 0);
            acQ[t] = __builtin_amdgcn_mfma_f32_16x16x32_bf16(aQ1, bfr[t][1], acQ[t], 0, 0, 0);
        }
        __syncthreads();
        aP0 = *reinterpret_cast<const short8*>(hP + aoff);       // h_P(k)
        aP1 = *reinterpret_cast<const short8*>(hP + aoff + 32);

        // ---- odd interval: act Q(k), MFMA P(k+1) ----
        float xp0 = xP0[k + 1], xp1 = xP1[k + 1];  // k=511: in-bounds garbage, result unused
        ACT(acQ, csQ, hvQ);
        hQ[woff] = f2bf(hvQ[0]); hQ[woff + HS] = f2bf(hvQ[1]);
        #pragma unroll
        for (int t = 0; t < 4; ++t) {
            acP[t][0] = fmaf(xp0, wih[t], bb[t]);
            acP[t][1] = fmaf(xp1, wih[t], bb[t]);
        }
        #pragma unroll
        for (int t = 0; t < 4; ++t) {
            acP[t] = __builtin_amdgcn_mfma_f32_16x16x32_bf16(aP0, bfr[t][0], acP[t], 0, 0, 0);
            acP[t] = __builtin_amdgcn_mfma_f32_16x16x32_bf16(aP1, bfr[t][1], acP[t], 0, 0, 0);
        }
        __syncthreads();
        aQ0 = *reinterpret_cast<const short8*>(hQ + aoff);       // h_Q(k)
        aQ1 = *reinterpret_cast<const short8*>(hQ + aoff + 32);
    }

    // hvP/hvQ hold h(511) for both groups
    hf[(2 * q) * 65 + n] = hvP[0];
    hf[(2 * q + 1) * 65 + n] = hvP[1];
    hf[(8 + 2 * q) * 65 + n] = hvQ[0];
    hf[(8 + 2 * q + 1) * 65 + n] = hvQ[1];
    __syncthreads();

    // head: out[b][o] = sum_n hf[b][n]*W_out[o][n] + b_out[o]
    if (tid < 16 * 3) {
        int row = tid / 3, o = tid % 3;
        float s = b_out[o];
        #pragma unroll 8
        for (int k = 0; k < HH; ++k) s = fmaf(hf[row * 65 + k], W_out[o * 64 + k], s);
        out[(size_t)(bbase + row) * 3 + o] = s;
    }
    #undef ACT
}

extern "C" void kernel_launch(void* const* d_in, const int* in_sizes, int n_in,
                              void* d_out, int out_size, void* d_ws, size_t ws_size,
                              hipStream_t stream) {
    const float* x     = (const float*)d_in[0];
    const float* W_ih  = (const float*)d_in[1];
    const float* W_hh  = (const float*)d_in[2];
    const float* b_ih  = (const float*)d_in[3];
    const float* b_hh  = (const float*)d_in[4];
    const float* W_out = (const float*)d_in[5];
    const float* b_out = (const float*)d_in[6];
    float* out = (float*)d_out;
    hipLaunchKernelGGL(lstm_kernel, dim3(BATCH / 16), dim3(256), 0, stream,
                       x, W_ih, W_hh, b_ih, b_hh, W_out, b_out, out);
}

// Round 13
// 270.879 us; speedup vs baseline: 1.4025x; 1.4025x over previous
//
#include <hip/hip_runtime.h>

#define BATCH 4096
#define TT 512
#define HH 64
#define BT 8       // batch rows per block; batch j at tile row 4*(j>>1)+(j&1) -> valid C/D slots r=0,1
#define XS 516     // x_s row stride in floats
#define HS 72      // h buffer row stride in bf16

typedef __attribute__((ext_vector_type(8))) short short8;
typedef __attribute__((ext_vector_type(4))) float floatx4;

__device__ __forceinline__ unsigned short f2bf(float f) {   // RNE f32->bf16
    unsigned u = __float_as_uint(f);
    u = u + 0x7FFFu + ((u >> 16) & 1u);
    return (unsigned short)(u >> 16);
}

// LOOKAHEAD PIPELINE at 2 blocks/CU. R11's interval order exposed ds_read
// (~120cyc) + MFMA drain (~90) BEFORE act in every interval. New order:
//   act(k) [acc drained under previous barrier] ; write h(k) ; hoisted x(k+1)
//   reads ; BARRIER ; read h(k) frags ; issue MFMA(k+1) -> drains under the
//   NEXT barrier + act.
// Every latency element now sits under the barrier or the next act's issue.
// + rcp-merge: the two cells' rcp pairs combined (rcp(a)rcp(b)=rcp(ab)):
//   4 rcp -> 2 rcp + 6 mul (trans 14->12 insts/wave-step).
// + prescaled gates (i,f,o: -log2e; g: +2log2e) from R11.
__global__ __launch_bounds__(256, 2) void lstm_kernel(
    const float* __restrict__ x, const float* __restrict__ W_ih,
    const float* __restrict__ W_hh, const float* __restrict__ b_ih,
    const float* __restrict__ b_hh, const float* __restrict__ W_out,
    const float* __restrict__ b_out, float* __restrict__ out)
{
    __shared__ __align__(16) float x_s[BT * XS];             // 16.5 KB
    __shared__ __align__(16) unsigned short hb0[16 * HS];    // h_k, k even; rows m&2 stay 0
    __shared__ __align__(16) unsigned short hb1[16 * HS];    // h_k, k odd
    __shared__ __align__(16) float hf[BT * 65];

    const int tid = threadIdx.x;
    const int w = tid >> 6;       // wave 0..3 -> gate col-tiles {w,w+4,w+8,w+12}
    const int l = tid & 63;
    const int q = l >> 4;
    const int c = l & 15;
    const int n = 16 * w + c;     // hidden index this lane activates
    const int bbase = blockIdx.x * BT;

    // stage x[bbase..bbase+7][0..511] into LDS, coalesced float4
    for (int i = 0; i < 4; ++i) {
        int flat = i * 256 + tid;              // 1024 float4s
        int row = flat >> 7, c4 = flat & 127;
        const float4* xg = reinterpret_cast<const float4*>(x + (size_t)(bbase + row) * TT);
        float4 v = xg[c4];
        *reinterpret_cast<float4*>(&x_s[row * XS + c4 * 4]) = v;
    }
    for (int i = tid; i < 16 * HS; i += 256) { hb0[i] = 0; hb1[i] = 0; }

    const float L1 = 1.44269504089f;      // log2(e)
    const float L2 = 2.88539008178f;      // 2*log2(e)

    // persistent B-fragments, PRE-SCALED: t=0(i),1(f),3(o): -log2e ; t=2(g): +2log2e
    short8 bfr[4][2];
    float wih[4], bb[4];
    for (int t = 0; t < 4; ++t) {
        float sc = (t == 2) ? L2 : -L1;
        int g = 64 * t + n;
        wih[t] = W_ih[g] * sc;
        bb[t] = (b_ih[g] + b_hh[g]) * sc;
        for (int ks = 0; ks < 2; ++ks) {
            const float* wp = W_hh + g * 64 + ks * 32 + q * 8;
            short8 v;
            #pragma unroll
            for (int j = 0; j < 8; ++j) v[j] = (short)f2bf(wp[j] * sc);
            bfr[t][ks] = v;
        }
    }

    float cst[2] = {0.f, 0.f};    // c-state, batch rows 2q+rr, hidden n
    float hvk[2] = {0.f, 0.f};    // current h (register)

    floatx4 acc[4];               // slots r=2,3 face zero A-rows: init once, stay 0
    #pragma unroll
    for (int t = 0; t < 4; ++t) acc[t] = floatx4{0.f, 0.f, 0.f, 0.f};

    const int aoff = c * HS + q * 8;      // A-frag LDS offset (shorts)
    const int woff = (4 * q) * HS + n;    // h write base; +HS for rr=1
    const float* xrowA = &x_s[(2 * q) * XS];
    const float* xrowB = &x_s[(2 * q + 1) * XS];

    __syncthreads();   // staging + zeroed h0 visible

    // Prologue: gates(0) = x_proj only (h(-1)=0 -> no MFMA needed)
    {
        float x0 = xrowA[0], x1 = xrowB[0];
        #pragma unroll
        for (int t = 0; t < 4; ++t) {
            acc[t][0] = fmaf(x0, wih[t], bb[t]);
            acc[t][1] = fmaf(x1, wih[t], bb[t]);
        }
    }

    for (int k = 0; k < TT - 1; ++k) {
        unsigned short* dst = (k & 1) ? hb1 : hb0;

        // ---- act(k): gates pre-scaled -> direct exp2; rcp-merged across cells ----
        float ei0 = __builtin_amdgcn_exp2f(acc[0][0]);
        float ef0 = __builtin_amdgcn_exp2f(acc[1][0]);
        float eg0 = __builtin_amdgcn_exp2f(acc[2][0]);
        float eo0 = __builtin_amdgcn_exp2f(acc[3][0]);
        float ei1 = __builtin_amdgcn_exp2f(acc[0][1]);
        float ef1 = __builtin_amdgcn_exp2f(acc[1][1]);
        float eg1 = __builtin_amdgcn_exp2f(acc[2][1]);
        float eo1 = __builtin_amdgcn_exp2f(acc[3][1]);

        float pf0 = 1.f + ef0, pg0 = (1.f + ei0) * (1.f + eg0);
        float pf1 = 1.f + ef1, pg1 = (1.f + ei1) * (1.f + eg1);
        float d0 = pf0 * pg0, d1 = pf1 * pg1;
        float rd = __builtin_amdgcn_rcpf(d0 * d1);          // merged rcp #1
        float num0 = fmaf(cst[0], pg0, (eg0 - 1.f) * pf0);
        float num1 = fmaf(cst[1], pg1, (eg1 - 1.f) * pf1);
        cst[0] = num0 * d1 * rd;
        cst[1] = num1 * d0 * rd;

        float ec0 = __builtin_amdgcn_exp2f(L2 * cst[0]);
        float ec1 = __builtin_amdgcn_exp2f(L2 * cst[1]);
        float e0 = (1.f + eo0) * (1.f + ec0);
        float e1 = (1.f + eo1) * (1.f + ec1);
        float re = __builtin_amdgcn_rcpf(e0 * e1);          // merged rcp #2
        hvk[0] = (ec0 - 1.f) * e1 * re;
        hvk[1] = (ec1 - 1.f) * e0 * re;

        dst[woff] = f2bf(hvk[0]);
        dst[woff + HS] = f2bf(hvk[1]);

        // hoist x(k+1) LDS reads: latency hides under the barrier
        float xa = xrowA[k + 1], xb = xrowB[k + 1];

        __syncthreads();

        // ---- read h(k) frags + issue MFMA(k+1); drains under next barrier+act ----
        short8 a0 = *reinterpret_cast<const short8*>(dst + aoff);
        short8 a1 = *reinterpret_cast<const short8*>(dst + aoff + 32);
        #pragma unroll
        for (int t = 0; t < 4; ++t) {
            acc[t][0] = fmaf(xa, wih[t], bb[t]);
            acc[t][1] = fmaf(xb, wih[t], bb[t]);
        }
        #pragma unroll
        for (int t = 0; t < 4; ++t) {
            acc[t] = __builtin_amdgcn_mfma_f32_16x16x32_bf16(a0, bfr[t][0], acc[t], 0, 0, 0);
            acc[t] = __builtin_amdgcn_mfma_f32_16x16x32_bf16(a1, bfr[t][1], acc[t], 0, 0, 0);
        }
    }

    // ---- final act(511) ----
    {
        float ei0 = __builtin_amdgcn_exp2f(acc[0][0]);
        float ef0 = __builtin_amdgcn_exp2f(acc[1][0]);
        float eg0 = __builtin_amdgcn_exp2f(acc[2][0]);
        float eo0 = __builtin_amdgcn_exp2f(acc[3][0]);
        float ei1 = __builtin_amdgcn_exp2f(acc[0][1]);
        float ef1 = __builtin_amdgcn_exp2f(acc[1][1]);
        float eg1 = __builtin_amdgcn_exp2f(acc[2][1]);
        float eo1 = __builtin_amdgcn_exp2f(acc[3][1]);
        float pf0 = 1.f + ef0, pg0 = (1.f + ei0) * (1.f + eg0);
        float pf1 = 1.f + ef1, pg1 = (1.f + ei1) * (1.f + eg1);
        float d0 = pf0 * pg0, d1 = pf1 * pg1;
        float rd = __builtin_amdgcn_rcpf(d0 * d1);
        float num0 = fmaf(cst[0], pg0, (eg0 - 1.f) * pf0);
        float num1 = fmaf(cst[1], pg1, (eg1 - 1.f) * pf1);
        cst[0] = num0 * d1 * rd;
        cst[1] = num1 * d0 * rd;
        float ec0 = __builtin_amdgcn_exp2f(L2 * cst[0]);
        float ec1 = __builtin_amdgcn_exp2f(L2 * cst[1]);
        float e0 = (1.f + eo0) * (1.f + ec0);
        float e1 = (1.f + eo1) * (1.f + ec1);
        float re = __builtin_amdgcn_rcpf(e0 * e1);
        hvk[0] = (ec0 - 1.f) * e1 * re;
        hvk[1] = (ec1 - 1.f) * e0 * re;
    }

    hf[(2 * q) * 65 + n] = hvk[0];
    hf[(2 * q + 1) * 65 + n] = hvk[1];
    __syncthreads();

    // head: out[b][o] = sum_n hf[b][n]*W_out[o][n] + b_out[o]
    if (tid < BT * 3) {
        int row = tid / 3, o = tid % 3;
        float s = b_out[o];
        #pragma unroll 8
        for (int k = 0; k < HH; ++k) s = fmaf(hf[row * 65 + k], W_out[o * 64 + k], s);
        out[(size_t)(bbase + row) * 3 + o] = s;
    }
}

extern "C" void kernel_launch(void* const* d_in, const int* in_sizes, int n_in,
                              void* d_out, int out_size, void* d_ws, size_t ws_size,
                              hipStream_t stream) {
    const float* x     = (const float*)d_in[0];
    const float* W_ih  = (const float*)d_in[1];
    const float* W_hh  = (const float*)d_in[2];
    const float* b_ih  = (const float*)d_in[3];
    const float* b_hh  = (const float*)d_in[4];
    const float* W_out = (const float*)d_in[5];
    const float* b_out = (const float*)d_in[6];
    float* out = (float*)d_out;
    hipLaunchKernelGGL(lstm_kernel, dim3(BATCH / BT), dim3(256), 0, stream,
                       x, W_ih, W_hh, b_ih, b_hh, W_out, b_out, out);
}